// Round 1
// baseline (258.403 us; speedup 1.0000x reference)
//
#include <hip/hip_runtime.h>
#include <stdint.h>

typedef unsigned short u16;
typedef unsigned int u32;
typedef __attribute__((ext_vector_type(8))) short bf16x8;
typedef __attribute__((ext_vector_type(4))) float f32x4;

#define DS 2048
#define NROWS 16384
#define MS 1024

#define BM 128
#define BN 128
#define BK 32

__device__ __forceinline__ u16 f2bf(float f) {
  u32 u = __float_as_uint(f);
  u32 r = (u + 0x7fffu + ((u >> 16) & 1u)) >> 16;
  return (u16)r;
}
__device__ __forceinline__ float bf2f(u16 h) {
  return __uint_as_float(((u32)h) << 16);
}

// ---------------- f32 -> bf16 convert (vectorized, grid-stride) ----------------
__global__ __launch_bounds__(256) void k_f32_to_bf16(const float* __restrict__ in,
                                                     u16* __restrict__ out, int n4) {
  int i = blockIdx.x * blockDim.x + threadIdx.x;
  int stride = gridDim.x * blockDim.x;
  for (; i < n4; i += stride) {
    float4 v = ((const float4*)in)[i];
    ushort4 o;
    o.x = f2bf(v.x);
    o.y = f2bf(v.y);
    o.z = f2bf(v.z);
    o.w = f2bf(v.w);
    ((ushort4*)out)[i] = o;
  }
}

// ---------------- async global->LDS, 16B per lane ----------------
__device__ __forceinline__ void gload16(const u16* g, u16* l) {
  __builtin_amdgcn_global_load_lds(
      (const __attribute__((address_space(1))) void*)g,
      (__attribute__((address_space(3))) void*)l, 16, 0, 0);
}

// ---------------- bt-GEMM: C[M][N] = A[M][K] @ Bt[N][K]^T, bf16 in, bf16 out ----
// m97 structure: 128x128 tile, 4 waves (2x2), each wave 64x64 = 4x4 frags of
// 16x16x32 MFMA. global_load_lds width-16 staging, 2 barriers per K-step.
__global__ __launch_bounds__(256, 2) void k_gemm_bt(const u16* __restrict__ A,
                                                    const u16* __restrict__ Bt,
                                                    u16* __restrict__ C, int M, int N,
                                                    int K) {
  __shared__ u16 lsA[BM * BK];
  __shared__ u16 lsB[BN * BK];
  const int tid = threadIdx.x;
  const int wid = tid >> 6;
  const int lane = tid & 63;
  const int brow = blockIdx.y * BM;
  const int bcol = blockIdx.x * BN;
  const int wm = wid >> 1;
  const int wn = wid & 1;

  f32x4 zero = {0.f, 0.f, 0.f, 0.f};
  f32x4 acc[4][4];
#pragma unroll
  for (int i = 0; i < 4; ++i)
#pragma unroll
    for (int j = 0; j < 4; ++j) acc[i][j] = zero;

  // staging: each wave stages 32 rows of A-tile and 32 rows of Bt-tile.
  // per instruction: 64 lanes x 16B = 16 rows (row = lane>>2, k-octet = lane&3).
  const int srow = lane >> 2;
  const int skoct = (lane & 3) * 8;
  const u16* gA = A + (size_t)(brow + wid * 32 + srow) * K + skoct;
  const u16* gB = Bt + (size_t)(bcol + wid * 32 + srow) * K + skoct;
  u16* lA0 = &lsA[(wid * 32) * BK];
  u16* lA1 = &lsA[(wid * 32 + 16) * BK];
  u16* lB0 = &lsB[(wid * 32) * BK];
  u16* lB1 = &lsB[(wid * 32 + 16) * BK];
  const size_t row16 = (size_t)16 * K;

  // fragment read indices (A: row = l&15, k = (l>>4)*8; B symmetric on Bt rows)
  const int arow = wm * 64 + (lane & 15);
  const int bcr = wn * 64 + (lane & 15);
  const int koff = (lane >> 4) * 8;

  for (int kt = 0; kt < K; kt += BK) {
    gload16(gA + kt, lA0);
    gload16(gA + kt + row16, lA1);
    gload16(gB + kt, lB0);
    gload16(gB + kt + row16, lB1);
    __syncthreads();  // drains vmcnt -> LDS tiles ready

    bf16x8 af[4], bfr[4];
#pragma unroll
    for (int i = 0; i < 4; ++i)
      af[i] = *(const bf16x8*)&lsA[(arow + i * 16) * BK + koff];
#pragma unroll
    for (int i = 0; i < 4; ++i)
      bfr[i] = *(const bf16x8*)&lsB[(bcr + i * 16) * BK + koff];
#pragma unroll
    for (int mi = 0; mi < 4; ++mi)
#pragma unroll
      for (int ni = 0; ni < 4; ++ni)
        acc[mi][ni] = __builtin_amdgcn_mfma_f32_16x16x32_bf16(af[mi], bfr[ni],
                                                              acc[mi][ni], 0, 0, 0);
    __syncthreads();  // compute done before next stage overwrites LDS
  }

  // C layout (verified m89/m91): col = lane&15, row = (lane>>4)*4 + reg
  const int crow0 = brow + wm * 64 + (lane >> 4) * 4;
  const int ccol0 = bcol + wn * 64 + (lane & 15);
#pragma unroll
  for (int mi = 0; mi < 4; ++mi)
#pragma unroll
    for (int ni = 0; ni < 4; ++ni)
#pragma unroll
      for (int r = 0; r < 4; ++r)
        C[(size_t)(crow0 + mi * 16 + r) * N + (ccol0 + ni * 16)] =
            f2bf(acc[mi][ni][r]);
}

// ---------------- per-row: softmax-weighted g, then log-sigmoid ----------------
// row layout: [0..1023] = raw s = D.S[m],  [1024..2047] = g = D.V[m]
__global__ __launch_bounds__(256) void k_reduce_rows(const u16* __restrict__ Cbf,
                                                     float* __restrict__ lsg) {
  const int i = blockIdx.x;
  const u16* row = Cbf + (size_t)i * 2048;
  const int t = threadIdx.x;
  const int lane = t & 63;
  const int wv = t >> 6;
  __shared__ float red[12];

  ushort4 sv = ((const ushort4*)row)[t];
  ushort4 gv = ((const ushort4*)(row + 1024))[t];
  const float inv = 0.022097086912079608f;  // 1/sqrt(2048)
  float s0 = bf2f(sv.x) * inv, s1 = bf2f(sv.y) * inv;
  float s2 = bf2f(sv.z) * inv, s3 = bf2f(sv.w) * inv;
  float g0 = bf2f(gv.x), g1 = bf2f(gv.y), g2 = bf2f(gv.z), g3 = bf2f(gv.w);

  float mx = fmaxf(fmaxf(s0, s1), fmaxf(s2, s3));
#pragma unroll
  for (int off = 32; off > 0; off >>= 1) mx = fmaxf(mx, __shfl_down(mx, off));
  if (lane == 0) red[wv] = mx;
  __syncthreads();
  if (t == 0) red[8] = fmaxf(fmaxf(red[0], red[1]), fmaxf(red[2], red[3]));
  __syncthreads();
  mx = red[8];

  float p0 = __expf(s0 - mx), p1 = __expf(s1 - mx);
  float p2 = __expf(s2 - mx), p3 = __expf(s3 - mx);
  float den = p0 + p1 + p2 + p3;
  float num = p0 * g0 + p1 * g1 + p2 * g2 + p3 * g3;
#pragma unroll
  for (int off = 32; off > 0; off >>= 1) {
    num += __shfl_down(num, off);
    den += __shfl_down(den, off);
  }
  if (lane == 0) {
    red[wv] = num;
    red[4 + wv] = den;
  }
  __syncthreads();
  if (t == 0) {
    float n = red[0] + red[1] + red[2] + red[3];
    float d = red[4] + red[5] + red[6] + red[7];
    float logit = n / d;
    float ls = (logit >= 0.f) ? -log1pf(__expf(-logit))
                              : (logit - log1pf(__expf(logit)));
    lsg[i] = ls;
  }
}

// ---------------- deterministic final sum (single block) ----------------
__global__ __launch_bounds__(1024) void k_final(const float* __restrict__ lsg,
                                                float* __restrict__ out, int n) {
  __shared__ float red[16];
  float s = 0.f;
  for (int i = threadIdx.x; i < n; i += 1024) s += lsg[i];
#pragma unroll
  for (int off = 32; off > 0; off >>= 1) s += __shfl_down(s, off);
  if ((threadIdx.x & 63) == 0) red[threadIdx.x >> 6] = s;
  __syncthreads();
  if (threadIdx.x == 0) {
    float t = 0.f;
#pragma unroll
    for (int k = 0; k < 16; ++k) t += red[k];
    out[0] = t;
  }
}

extern "C" void kernel_launch(void* const* d_in, const int* in_sizes, int n_in,
                              void* d_out, int out_size, void* d_ws, size_t ws_size,
                              hipStream_t stream) {
  const float* D = (const float*)d_in[0];
  const float* S = (const float*)d_in[1];
  const float* W = (const float*)d_in[2];

  char* w = (char*)d_ws;
  u16* Dbf = (u16*)w;
  w += (size_t)NROWS * DS * 2;  // 67 MB
  u16* Bt = (u16*)w;            // rows 0..1023 = Sbf, rows 1024..2047 = V bf16
  w += (size_t)2 * MS * DS * 2; // 8 MB
  u16* Wbf = (u16*)w;
  w += (size_t)DS * DS * 2;     // 8 MB
  u16* Cbf = (u16*)w;
  w += (size_t)NROWS * 2 * MS * 2;  // 67 MB
  float* lsg = (float*)w;       // 64 KB

  // converts
  k_f32_to_bf16<<<2048, 256, 0, stream>>>(W, Wbf, DS * DS / 4);
  k_f32_to_bf16<<<1024, 256, 0, stream>>>(S, Bt, MS * DS / 4);
  k_f32_to_bf16<<<2048, 256, 0, stream>>>(D, Dbf, NROWS * DS / 4);

  // V = S @ W^T  -> Bt rows 1024..2047   (A = Sbf = Bt rows 0..1023)
  k_gemm_bt<<<dim3(DS / BN, MS / BM), 256, 0, stream>>>(
      Bt, Wbf, Bt + (size_t)MS * DS, MS, DS, DS);

  // C = Dbf @ [S;V]^T : cols 0..1023 = s, cols 1024..2047 = g
  k_gemm_bt<<<dim3((2 * MS) / BN, NROWS / BM), 256, 0, stream>>>(
      Dbf, Bt, Cbf, NROWS, 2 * MS, DS);

  k_reduce_rows<<<NROWS, 256, 0, stream>>>(Cbf, lsg);
  k_final<<<1, 1024, 0, stream>>>(lsg, (float*)d_out, NROWS);
}

// Round 2
// 200.872 us; speedup vs baseline: 1.2864x; 1.2864x over previous
//
#include <hip/hip_runtime.h>
#include <stdint.h>

typedef unsigned short u16;
typedef unsigned int u32;
typedef __attribute__((ext_vector_type(8))) short bf16x8;
typedef __attribute__((ext_vector_type(4))) float f32x4;

#define DS 2048
#define NROWS 16384
#define MS 1024
#define K2 2048

__device__ __forceinline__ u16 f2bf(float f) {
  u32 u = __float_as_uint(f);
  u32 r = (u + 0x7fffu + ((u >> 16) & 1u)) >> 16;
  return (u16)r;
}
__device__ __forceinline__ float bf2f(u16 h) {
  return __uint_as_float(((u32)h) << 16);
}

// ---------------- f32 -> bf16 converts ----------------
__global__ __launch_bounds__(256) void k_conv(const float* __restrict__ in,
                                              u16* __restrict__ out, int n4) {
  int i = blockIdx.x * blockDim.x + threadIdx.x;
  int stride = gridDim.x * blockDim.x;
  for (; i < n4; i += stride) {
    float4 v = ((const float4*)in)[i];
    ushort4 o;
    o.x = f2bf(v.x); o.y = f2bf(v.y); o.z = f2bf(v.z); o.w = f2bf(v.w);
    ((ushort4*)out)[i] = o;
  }
}

// S convert: writes contiguous Sbf AND interleaved Bt even rows (row 2m = S[m])
__global__ __launch_bounds__(256) void k_conv_S(const float* __restrict__ in,
                                                u16* __restrict__ Sbf,
                                                u16* __restrict__ Bt, int n4) {
  int i = blockIdx.x * blockDim.x + threadIdx.x;
  int stride = gridDim.x * blockDim.x;
  for (; i < n4; i += stride) {
    float4 v = ((const float4*)in)[i];
    ushort4 o;
    o.x = f2bf(v.x); o.y = f2bf(v.y); o.z = f2bf(v.z); o.w = f2bf(v.w);
    ((ushort4*)Sbf)[i] = o;
    int m = i >> 9;           // 512 float4 per row of 2048
    int c4 = i & 511;
    ((ushort4*)Bt)[(size_t)m * 1024 + c4] = o;  // row 2m
  }
}

// ---------------- async global->LDS, 16B per lane ----------------
__device__ __forceinline__ void gload16(const u16* g, u16* l) {
  __builtin_amdgcn_global_load_lds(
      (const __attribute__((address_space(1))) void*)g,
      (__attribute__((address_space(3))) void*)l, 16, 0, 0);
}

// ---------------- m97-style 128^2 bt-GEMM (for V = S @ W^T), verified r0 ------
__global__ __launch_bounds__(256, 2) void k_gemm_bt(const u16* __restrict__ A,
                                                    const u16* __restrict__ Bt,
                                                    u16* __restrict__ C, int ldc,
                                                    int M, int N, int K) {
  __shared__ u16 lsA[128 * 32];
  __shared__ u16 lsB[128 * 32];
  const int tid = threadIdx.x;
  const int wid = tid >> 6;
  const int lane = tid & 63;
  const int brow = blockIdx.y * 128;
  const int bcol = blockIdx.x * 128;
  const int wm = wid >> 1;
  const int wn = wid & 1;

  f32x4 zero = {0.f, 0.f, 0.f, 0.f};
  f32x4 acc[4][4];
#pragma unroll
  for (int i = 0; i < 4; ++i)
#pragma unroll
    for (int j = 0; j < 4; ++j) acc[i][j] = zero;

  const int srow = lane >> 2;
  const int skoct = (lane & 3) * 8;
  const u16* gA = A + (size_t)(brow + wid * 32 + srow) * K + skoct;
  const u16* gB = Bt + (size_t)(bcol + wid * 32 + srow) * K + skoct;
  u16* lA0 = &lsA[(wid * 32) * 32];
  u16* lA1 = &lsA[(wid * 32 + 16) * 32];
  u16* lB0 = &lsB[(wid * 32) * 32];
  u16* lB1 = &lsB[(wid * 32 + 16) * 32];
  const size_t row16 = (size_t)16 * K;

  const int arow = wm * 64 + (lane & 15);
  const int bcr = wn * 64 + (lane & 15);
  const int koff = (lane >> 4) * 8;

  for (int kt = 0; kt < K; kt += 32) {
    gload16(gA + kt, lA0);
    gload16(gA + kt + row16, lA1);
    gload16(gB + kt, lB0);
    gload16(gB + kt + row16, lB1);
    __syncthreads();

    bf16x8 af[4], bfr[4];
#pragma unroll
    for (int i = 0; i < 4; ++i) af[i] = *(const bf16x8*)&lsA[(arow + i * 16) * 32 + koff];
#pragma unroll
    for (int i = 0; i < 4; ++i) bfr[i] = *(const bf16x8*)&lsB[(bcr + i * 16) * 32 + koff];
#pragma unroll
    for (int mi = 0; mi < 4; ++mi)
#pragma unroll
      for (int ni = 0; ni < 4; ++ni)
        acc[mi][ni] = __builtin_amdgcn_mfma_f32_16x16x32_bf16(af[mi], bfr[ni],
                                                              acc[mi][ni], 0, 0, 0);
    __syncthreads();
  }

  const int crow0 = brow + wm * 64 + (lane >> 4) * 4;
  const int ccol0 = bcol + wn * 64 + (lane & 15);
#pragma unroll
  for (int mi = 0; mi < 4; ++mi)
#pragma unroll
    for (int ni = 0; ni < 4; ++ni)
#pragma unroll
      for (int r = 0; r < 4; ++r)
        C[(size_t)(crow0 + mi * 16 + r) * ldc + (ccol0 + ni * 16)] = f2bf(acc[mi][ni][r]);
}

// ================= 256^2 8-phase GEMM with fused softmax-pair epilogue =========
// C = Dbf[16384x2048] @ Bt[2048x2048]^T. Bt rows interleaved: 2m=S[m], 2m+1=V[m].
// Epilogue: per output row, partial num = sum exp(s_m/sqrt(Ds))*g_m, den = sum exp.
// Writes Pnd[row][8 colblocks][2].
#define SINV 0.022097086912079608f

#define DSR(dst, addr) asm volatile("ds_read_b128 %0, %1" : "=v"(dst) : "v"(addr))

#define AADDR(B, QM, MI, KK) \
  ((abase + (B) * 65536u + (QM) * 16384u + (MI) * 2048u) ^ ((KK) * 64u))
#define BADDR(B, QN, NI, KK) \
  ((bbase + (B) * 65536u + (QN) * 16384u + (NI) * 2048u) ^ ((KK) * 64u))

// stage one half-tile (2 x global_load_lds). AB: 0=A,1=B. h: row-half. kt: k elem.
#define STG(gptr, b, AB, h, kt)                                                     \
  do {                                                                              \
    gload16(gptr + (size_t)((h) * 128) * K2 + (kt),                                 \
            &lds[(b) * 32768 + (AB) * 16384 + (h) * 8192 + wid * 512]);             \
    gload16(gptr + (size_t)((h) * 128 + 64) * K2 + (kt),                            \
            &lds[(b) * 32768 + (AB) * 16384 + (h) * 8192 + 4096 + wid * 512]);      \
  } while (0)
#define STG_A(b, h, kt) STG(gAs, b, 0, h, kt)
#define STG_B(b, h, kt) STG(gBs, b, 1, h, kt)

#define RD_ALPHA(B)                                                   \
  do {                                                                \
    _Pragma("unroll") for (int mi = 0; mi < 4; ++mi) {                \
      DSR(af[mi][0], AADDR(B, 0, mi, 0));                             \
      DSR(af[mi][1], AADDR(B, 0, mi, 1));                             \
    }                                                                 \
    _Pragma("unroll") for (int ni = 0; ni < 2; ++ni) {                \
      DSR(bq[0][ni][0], BADDR(B, 0, ni, 0));                          \
      DSR(bq[0][ni][1], BADDR(B, 0, ni, 1));                          \
    }                                                                 \
  } while (0)
#define RD_BETA(B)                                                    \
  do {                                                                \
    _Pragma("unroll") for (int ni = 0; ni < 2; ++ni) {                \
      DSR(bq[1][ni][0], BADDR(B, 1, ni, 0));                          \
      DSR(bq[1][ni][1], BADDR(B, 1, ni, 1));                          \
    }                                                                 \
  } while (0)
#define RD_GAMMA(B)                                                   \
  do {                                                                \
    _Pragma("unroll") for (int mi = 0; mi < 4; ++mi) {                \
      DSR(af[mi][0], AADDR(B, 1, mi, 0));                             \
      DSR(af[mi][1], AADDR(B, 1, mi, 1));                             \
    }                                                                 \
  } while (0)

#define MMAQ(QM, QN)                                                               \
  do {                                                                             \
    _Pragma("unroll") for (int mi = 0; mi < 4; ++mi)                               \
        _Pragma("unroll") for (int ni = 0; ni < 2; ++ni) {                         \
      acc[QM][QN][mi][ni] = __builtin_amdgcn_mfma_f32_16x16x32_bf16(               \
          af[mi][0], bq[QN][ni][0], acc[QM][QN][mi][ni], 0, 0, 0);                 \
      acc[QM][QN][mi][ni] = __builtin_amdgcn_mfma_f32_16x16x32_bf16(               \
          af[mi][1], bq[QN][ni][1], acc[QM][QN][mi][ni], 0, 0, 0);                 \
    }                                                                              \
  } while (0)

#define PH_MID()                                              \
  __builtin_amdgcn_s_barrier();                               \
  asm volatile("s_waitcnt lgkmcnt(0)" ::: "memory");          \
  __builtin_amdgcn_sched_barrier(0);                          \
  __builtin_amdgcn_s_setprio(1)
#define PH_END() __builtin_amdgcn_s_setprio(0)
#define BAR() __builtin_amdgcn_s_barrier()
#define VM6() asm volatile("s_waitcnt vmcnt(6)" ::: "memory")
#define VM0() asm volatile("s_waitcnt vmcnt(0)" ::: "memory")

__global__ __launch_bounds__(512, 2) void k_gemm8(const u16* __restrict__ A,
                                                  const u16* __restrict__ Bt,
                                                  float* __restrict__ Pnd) {
  extern __shared__ u16 lds[];
  const int tid = threadIdx.x;
  const int wid = tid >> 6;
  const int lane = tid & 63;
  const int bid = blockIdx.x;
  // XCD-aware swizzle (bijective: 512 % 8 == 0): each XCD gets 8 row-blocks x 8 col-blocks
  const int swz = (bid & 7) * 64 + (bid >> 3);
  const int by = swz >> 3, bx = swz & 7;
  const int brow = by * 256, bcol = bx * 256;
  const int wm = wid >> 2, wn = wid & 3;
  const int l15 = lane & 15, s0 = lane >> 4;

  // staging source addressing (pre-swizzled global source; LDS dest linear)
  const int tr = tid >> 3;
  const int scol = ((tid & 7) ^ (tr & 7)) << 3;
  const u16* gAs = A + (size_t)(brow + tr) * K2 + scol;
  const u16* gBs = Bt + (size_t)(bcol + tr) * K2 + scol;

  // LDS byte addressing for ds_read (low-32 of flat addr == LDS offset)
  const u32 lb = (u32)(uintptr_t)(&lds[0]);
  const u32 xorp = ((u32)(s0 ^ (lane & 7))) << 4;
  const u32 abase = lb + ((u32)(wm * 64 + l15) << 7) + xorp;
  const u32 bbase = lb + 32768u + ((u32)(wn * 32 + l15) << 7) + xorp;

  f32x4 acc[2][2][4][2];
#pragma unroll
  for (int a = 0; a < 2; ++a)
#pragma unroll
    for (int b = 0; b < 2; ++b)
#pragma unroll
      for (int c = 0; c < 4; ++c)
#pragma unroll
        for (int d = 0; d < 2; ++d) acc[a][b][c][d] = (f32x4){0.f, 0.f, 0.f, 0.f};

  bf16x8 af[4][2], bq[2][2][2];

  // prologue: t0 {Ah0,Bh0,Bh1,Ah1}, t1 {Ah0,Bh0,Bh1}; 3 half-tiles in flight
  STG_A(0, 0, 0); STG_B(0, 0, 0); STG_B(0, 1, 0); STG_A(0, 1, 0);
  STG_A(1, 0, 64); STG_B(1, 0, 64); STG_B(1, 1, 64);
  VM6();
  BAR();

  int kt0 = 0;
#pragma unroll 1
  for (int j = 0; j < 15; ++j, kt0 += 128) {
    const int kt1 = kt0 + 64, ktn0 = kt0 + 128, ktn1 = kt0 + 192;
    // P1..P4: consume buf0 (tile 2j)
    RD_ALPHA(0); STG_A(1, 1, kt1);  PH_MID(); MMAQ(0, 0); PH_END(); BAR();
    RD_BETA(0);  STG_A(0, 0, ktn0); PH_MID(); MMAQ(0, 1); PH_END(); BAR();
    RD_GAMMA(0); STG_B(0, 0, ktn0); PH_MID(); MMAQ(1, 0); PH_END(); BAR();
    STG_B(0, 1, ktn0);              PH_MID(); MMAQ(1, 1); PH_END(); VM6(); BAR();
    // P5..P8: consume buf1 (tile 2j+1)
    RD_ALPHA(1); STG_A(0, 1, ktn0); PH_MID(); MMAQ(0, 0); PH_END(); BAR();
    RD_BETA(1);  STG_A(1, 0, ktn1); PH_MID(); MMAQ(0, 1); PH_END(); BAR();
    RD_GAMMA(1); STG_B(1, 0, ktn1); PH_MID(); MMAQ(1, 0); PH_END(); BAR();
    STG_B(1, 1, ktn1);              PH_MID(); MMAQ(1, 1); PH_END(); VM6(); BAR();
  }
  // tail iteration j=15 (tiles 30,31): only stage is t31.Ah1
  {
    const int kt1 = kt0 + 64;
    RD_ALPHA(0); STG_A(1, 1, kt1);  PH_MID(); MMAQ(0, 0); PH_END(); BAR();
    RD_BETA(0);                     PH_MID(); MMAQ(0, 1); PH_END(); BAR();
    RD_GAMMA(0);                    PH_MID(); MMAQ(1, 0); PH_END(); BAR();
                                    PH_MID(); MMAQ(1, 1); PH_END(); VM0(); BAR();
    RD_ALPHA(1);                    PH_MID(); MMAQ(0, 0); PH_END(); BAR();
    RD_BETA(1);                     PH_MID(); MMAQ(0, 1); PH_END(); BAR();
    RD_GAMMA(1);                    PH_MID(); MMAQ(1, 0); PH_END(); BAR();
                                    PH_MID(); MMAQ(1, 1); PH_END(); BAR();
  }

  // ---------------- fused epilogue ----------------
  // col = qn*128 + wn*32 + ni*16 + l15 ; even col = s_m, odd col = g_m (pairs adjacent lanes)
  // row = qm*128 + wm*64 + mi*16 + s0*4 + r
  __syncthreads();  // drain everything; reuse LDS as f32 scratch
  float* red = (float*)&lds[0];  // [8 waves][32 slots][4 lanegroups][2]

#pragma unroll
  for (int qm = 0; qm < 2; ++qm)
#pragma unroll
    for (int mi = 0; mi < 4; ++mi)
#pragma unroll
      for (int r = 0; r < 4; ++r) {
        float num = 0.f, den = 0.f;
#pragma unroll
        for (int qn = 0; qn < 2; ++qn)
#pragma unroll
          for (int ni = 0; ni < 2; ++ni) {
            float v = acc[qm][qn][mi][ni][r];
            float g = __shfl_xor(v, 1);
            float e = __expf(v * SINV);
            num += e * g;
            den += e;
          }
        num += __shfl_xor(num, 2); den += __shfl_xor(den, 2);
        num += __shfl_xor(num, 4); den += __shfl_xor(den, 4);
        num += __shfl_xor(num, 8); den += __shfl_xor(den, 8);
        if (l15 == 0) {
          int slot = qm * 16 + mi * 4 + r;
          red[((wid * 32 + slot) * 4 + s0) * 2 + 0] = num;
          red[((wid * 32 + slot) * 4 + s0) * 2 + 1] = den;
        }
      }
  __syncthreads();
  {
    int rloc = tid >> 1, which = tid & 1;
    int qm = rloc >> 7, wmr = (rloc >> 6) & 1, mi = (rloc >> 4) & 3;
    int lg = (rloc >> 2) & 3, r = rloc & 3;
    int slot = qm * 16 + mi * 4 + r;
    float v = 0.f;
#pragma unroll
    for (int w2 = 0; w2 < 4; ++w2)
      v += red[(((wmr * 4 + w2) * 32 + slot) * 4 + lg) * 2 + which];
    Pnd[((size_t)(brow + rloc) * 8 + bx) * 2 + which] = v;
  }
}

// ---------------- per-row finish: logit = num/den, log-sigmoid, block-sum ------
__global__ __launch_bounds__(256) void k_rowfinal(const float* __restrict__ Pnd,
                                                  float* __restrict__ part) {
  int row = blockIdx.x * 256 + threadIdx.x;
  const float4* p = (const float4*)(Pnd + (size_t)row * 16);
  float num = 0.f, den = 0.f;
#pragma unroll
  for (int i = 0; i < 4; ++i) {
    float4 v = p[i];
    num += v.x + v.z;
    den += v.y + v.w;
  }
  float logit = num / den;
  float ls = (logit >= 0.f) ? -log1pf(__expf(-logit))
                            : (logit - log1pf(__expf(logit)));
  __shared__ float red[4];
#pragma unroll
  for (int off = 32; off > 0; off >>= 1) ls += __shfl_down(ls, off);
  if ((threadIdx.x & 63) == 0) red[threadIdx.x >> 6] = ls;
  __syncthreads();
  if (threadIdx.x == 0) part[blockIdx.x] = red[0] + red[1] + red[2] + red[3];
}

__global__ __launch_bounds__(64) void k_final64(const float* __restrict__ part,
                                                float* __restrict__ out) {
  float v = part[threadIdx.x];
#pragma unroll
  for (int off = 32; off > 0; off >>= 1) v += __shfl_down(v, off);
  if (threadIdx.x == 0) out[0] = v;
}

extern "C" void kernel_launch(void* const* d_in, const int* in_sizes, int n_in,
                              void* d_out, int out_size, void* d_ws, size_t ws_size,
                              hipStream_t stream) {
  const float* D = (const float*)d_in[0];
  const float* S = (const float*)d_in[1];
  const float* W = (const float*)d_in[2];

  char* w = (char*)d_ws;
  u16* Dbf = (u16*)w; w += (size_t)NROWS * DS * 2;       // 67 MB
  u16* Bt = (u16*)w;  w += (size_t)DS * DS * 2;          // 8 MB (interleaved S/V)
  u16* Wbf = (u16*)w; w += (size_t)DS * DS * 2;          // 8 MB
  u16* Sbf = (u16*)w; w += (size_t)MS * DS * 2;          // 4 MB
  float* Pnd = (float*)w; w += (size_t)NROWS * 16 * 4;   // 1 MB
  float* part = (float*)w;                               // 256 B

  (void)hipFuncSetAttribute((const void*)k_gemm8,
                            hipFuncAttributeMaxDynamicSharedMemorySize, 131072);

  k_conv<<<1024, 256, 0, stream>>>(W, Wbf, DS * DS / 4);
  k_conv_S<<<512, 256, 0, stream>>>(S, Sbf, Bt, MS * DS / 4);
  k_conv<<<2048, 256, 0, stream>>>(D, Dbf, NROWS * DS / 4);

  // V = S @ W^T, written to Bt odd rows (ldc = 4096, base = Bt + 2048)
  k_gemm_bt<<<dim3(DS / 128, MS / 128), 256, 0, stream>>>(
      Sbf, Wbf, Bt + DS, 2 * DS, MS, DS, DS);

  // fused main GEMM + softmax-pair epilogue
  k_gemm8<<<512, 512, 131072, stream>>>(Dbf, Bt, Pnd);

  k_rowfinal<<<NROWS / 256, 256, 0, stream>>>(Pnd, part);
  k_final64<<<1, 64, 0, stream>>>(part, (float*)d_out);
}

// Round 4
// 188.746 us; speedup vs baseline: 1.3690x; 1.0642x over previous
//
#include <hip/hip_runtime.h>
#include <stdint.h>

typedef unsigned short u16;
typedef unsigned int u32;
typedef __attribute__((ext_vector_type(8))) short bf16x8;
typedef __attribute__((ext_vector_type(4))) float f32x4;

#define DS 2048
#define NROWS 16384
#define MS 1024
#define K2 2048

__device__ __forceinline__ u16 f2bf(float f) {
  u32 u = __float_as_uint(f);
  u32 r = (u + 0x7fffu + ((u >> 16) & 1u)) >> 16;
  return (u16)r;
}
__device__ __forceinline__ float bf2f(u16 h) {
  return __uint_as_float(((u32)h) << 16);
}

// ---------------- f32 -> bf16 converts ----------------
__global__ __launch_bounds__(256) void k_conv(const float* __restrict__ in,
                                              u16* __restrict__ out, int n4) {
  int i = blockIdx.x * blockDim.x + threadIdx.x;
  int stride = gridDim.x * blockDim.x;
  for (; i < n4; i += stride) {
    float4 v = ((const float4*)in)[i];
    ushort4 o;
    o.x = f2bf(v.x); o.y = f2bf(v.y); o.z = f2bf(v.z); o.w = f2bf(v.w);
    ((ushort4*)out)[i] = o;
  }
}

__global__ __launch_bounds__(256) void k_conv_S(const float* __restrict__ in,
                                                u16* __restrict__ Sbf,
                                                u16* __restrict__ Bt, int n4) {
  int i = blockIdx.x * blockDim.x + threadIdx.x;
  int stride = gridDim.x * blockDim.x;
  for (; i < n4; i += stride) {
    float4 v = ((const float4*)in)[i];
    ushort4 o;
    o.x = f2bf(v.x); o.y = f2bf(v.y); o.z = f2bf(v.z); o.w = f2bf(v.w);
    ((ushort4*)Sbf)[i] = o;
    int m = i >> 9;
    int c4 = i & 511;
    ((ushort4*)Bt)[(size_t)m * 1024 + c4] = o;  // interleaved row 2m = S[m]
  }
}

// ---------------- async global->LDS, 16B per lane ----------------
__device__ __forceinline__ void gload16(const u16* g, u16* l) {
  __builtin_amdgcn_global_load_lds(
      (const __attribute__((address_space(1))) void*)g,
      (__attribute__((address_space(3))) void*)l, 16, 0, 0);
}

// ---------------- 64x128 bt-GEMM for V = S @ W^T (256 blocks) ----------------
__global__ __launch_bounds__(256, 2) void k_gemm_bt64(const u16* __restrict__ A,
                                                      const u16* __restrict__ Bt,
                                                      u16* __restrict__ C, int ldc,
                                                      int K) {
  __shared__ u16 lsA[64 * 32];
  __shared__ u16 lsB[128 * 32];
  const int tid = threadIdx.x;
  const int wid = tid >> 6;
  const int lane = tid & 63;
  const int brow = blockIdx.y * 64;
  const int bcol = blockIdx.x * 128;
  const int wm = wid >> 1;
  const int wn = wid & 1;

  f32x4 acc[2][4];
#pragma unroll
  for (int i = 0; i < 2; ++i)
#pragma unroll
    for (int j = 0; j < 4; ++j) acc[i][j] = (f32x4){0.f, 0.f, 0.f, 0.f};

  const int srow = lane >> 2;
  const int skoct = (lane & 3) * 8;
  const u16* gA = A + (size_t)(brow + wid * 16 + srow) * K + skoct;
  const u16* gB = Bt + (size_t)(bcol + wid * 32 + srow) * K + skoct;
  u16* lA = &lsA[(wid * 16) * 32];
  u16* lB0 = &lsB[(wid * 32) * 32];
  u16* lB1 = &lsB[(wid * 32 + 16) * 32];
  const size_t row16 = (size_t)16 * K;

  const int arow = wm * 32 + (lane & 15);
  const int bcr = wn * 64 + (lane & 15);
  const int koff = (lane >> 4) * 8;

  for (int kt = 0; kt < K; kt += 32) {
    gload16(gA + kt, lA);
    gload16(gB + kt, lB0);
    gload16(gB + kt + row16, lB1);
    __syncthreads();
    bf16x8 af[2], bfr[4];
#pragma unroll
    for (int i = 0; i < 2; ++i) af[i] = *(const bf16x8*)&lsA[(arow + i * 16) * 32 + koff];
#pragma unroll
    for (int i = 0; i < 4; ++i) bfr[i] = *(const bf16x8*)&lsB[(bcr + i * 16) * 32 + koff];
#pragma unroll
    for (int mi = 0; mi < 2; ++mi)
#pragma unroll
      for (int ni = 0; ni < 4; ++ni)
        acc[mi][ni] = __builtin_amdgcn_mfma_f32_16x16x32_bf16(af[mi], bfr[ni],
                                                              acc[mi][ni], 0, 0, 0);
    __syncthreads();
  }

  const int crow0 = brow + wm * 32 + (lane >> 4) * 4;
  const int ccol0 = bcol + wn * 64 + (lane & 15);
#pragma unroll
  for (int mi = 0; mi < 2; ++mi)
#pragma unroll
    for (int ni = 0; ni < 4; ++ni)
#pragma unroll
      for (int r = 0; r < 4; ++r)
        C[(size_t)(crow0 + mi * 16 + r) * ldc + (ccol0 + ni * 16)] = f2bf(acc[mi][ni][r]);
}

// ================= 256^2 read-ahead 8-phase GEMM + fused softmax epilogue ======
// C = Dbf[16384x2048] @ Bt[2048x2048]^T, Bt rows interleaved (2m=S, 2m+1=V).
// Pipeline: phase p's ds_reads feed phase p+1's MFMA; counted lgkmcnt/vmcnt;
// ONE barrier per phase. LDS XOR-swizzle, linear dest + pre-swizzled source.
// r4 FIX: P1/P2 (and tail T1/T2) must read the CURRENT buffer (buf0 bases
// aB00/aA00), not buf1 — r3 read uninitialized/stale buf1 -> NaN.
#define SINV 0.022097086912079608f

#define DSR(d, a, IMM) \
  asm volatile("ds_read_b128 %0, %1 offset:%c2" : "=v"(d) : "v"(a), "n"(IMM))

#define RD_A0(k0, k1, dst)                              \
  DSR(dst[0][0], k0, 0);     DSR(dst[0][1], k1, 0);     \
  DSR(dst[1][0], k0, 2048);  DSR(dst[1][1], k1, 2048);  \
  DSR(dst[2][0], k0, 4096);  DSR(dst[2][1], k1, 4096);  \
  DSR(dst[3][0], k0, 6144);  DSR(dst[3][1], k1, 6144)
#define RD_A1(k0, k1, dst)                              \
  DSR(dst[0][0], k0, 16384); DSR(dst[0][1], k1, 16384); \
  DSR(dst[1][0], k0, 18432); DSR(dst[1][1], k1, 18432); \
  DSR(dst[2][0], k0, 20480); DSR(dst[2][1], k1, 20480); \
  DSR(dst[3][0], k0, 22528); DSR(dst[3][1], k1, 22528)
#define RD_B0(k0, k1, dst)                              \
  DSR(dst[0][0], k0, 0);     DSR(dst[0][1], k1, 0);     \
  DSR(dst[1][0], k0, 2048);  DSR(dst[1][1], k1, 2048)
#define RD_B1(k0, k1, dst)                              \
  DSR(dst[0][0], k0, 16384); DSR(dst[0][1], k1, 16384); \
  DSR(dst[1][0], k0, 18432); DSR(dst[1][1], k1, 18432)

#define MMAQ(AF, BQ, QM, QN)                                                       \
  do {                                                                             \
    _Pragma("unroll") for (int mi = 0; mi < 4; ++mi)                               \
        _Pragma("unroll") for (int ni = 0; ni < 2; ++ni) {                         \
      acc[QM][QN][mi][ni] = __builtin_amdgcn_mfma_f32_16x16x32_bf16(               \
          AF[mi][0], BQ[ni][0], acc[QM][QN][mi][ni], 0, 0, 0);                     \
      acc[QM][QN][mi][ni] = __builtin_amdgcn_mfma_f32_16x16x32_bf16(               \
          AF[mi][1], BQ[ni][1], acc[QM][QN][mi][ni], 0, 0, 0);                     \
    }                                                                              \
  } while (0)

#define LGKM(N)                                              \
  asm volatile("s_waitcnt lgkmcnt(" #N ")" ::: "memory");    \
  __builtin_amdgcn_sched_barrier(0)
#define VMW(N) asm volatile("s_waitcnt vmcnt(" #N ")" ::: "memory")
#define PRIO1() __builtin_amdgcn_s_setprio(1)
#define PRIO0() __builtin_amdgcn_s_setprio(0)
#define BAR() __builtin_amdgcn_s_barrier()

// stage one half-tile: h row-half; kt k-element offset
#define STGA(b, h, kt)                                                            \
  do {                                                                            \
    gload16(pA + (size_t)((h) * 128) * K2 + (kt),                                 \
            &lds[(b) * 32768 + (h) * 8192 + wid * 512]);                          \
    gload16(pA + (size_t)((h) * 128 + 64) * K2 + (kt),                            \
            &lds[(b) * 32768 + (h) * 8192 + 4096 + wid * 512]);                   \
  } while (0)
#define STGB(b, h, kt)                                                            \
  do {                                                                            \
    gload16(pB + (size_t)((h) * 128) * K2 + (kt),                                 \
            &lds[(b) * 32768 + 16384 + (h) * 8192 + wid * 512]);                  \
    gload16(pB + (size_t)((h) * 128 + 64) * K2 + (kt),                            \
            &lds[(b) * 32768 + 16384 + (h) * 8192 + 4096 + wid * 512]);           \
  } while (0)

__global__ __launch_bounds__(512, 2) void k_gemm8(const u16* __restrict__ A,
                                                  const u16* __restrict__ Bt,
                                                  float* __restrict__ Pnd) {
  extern __shared__ u16 lds[];
  const int tid = threadIdx.x;
  const int wid = tid >> 6;
  const int lane = tid & 63;
  const int bid = blockIdx.x;
  const int swz = (bid & 7) * 64 + (bid >> 3);
  const int by = swz >> 3, bx = swz & 7;
  const int brow = by * 256, bcol = bx * 256;
  const int wm = wid >> 2, wn = wid & 3;
  const int l15 = lane & 15, s0 = lane >> 4;

  // pre-swizzled global source (LDS dest linear; involution on 16B octets)
  const int tr = tid >> 3;
  const int scol = ((tid & 7) ^ (tr & 7)) << 3;
  const u16* pA = A + (size_t)(brow + tr) * K2 + scol;
  const u16* pB = Bt + (size_t)(bcol + tr) * K2 + scol;

  // ds_read base addresses (8 regs; kk folded via XOR-64, buf via +65536)
  const u32 lb = (u32)(uintptr_t)(&lds[0]);
  const u32 xorp = ((u32)(s0 ^ (lane & 7))) << 4;
  const u32 aA00 = lb + ((u32)(wm * 64 + l15) << 7) + xorp;
  const u32 aA01 = aA00 ^ 64u;
  const u32 aA10 = aA00 + 65536u;
  const u32 aA11 = aA10 ^ 64u;
  const u32 aB00 = lb + 32768u + ((u32)(wn * 32 + l15) << 7) + xorp;
  const u32 aB01 = aB00 ^ 64u;
  const u32 aB10 = aB00 + 65536u;
  const u32 aB11 = aB10 ^ 64u;

  f32x4 acc[2][2][4][2];
#pragma unroll
  for (int a = 0; a < 2; ++a)
#pragma unroll
    for (int b = 0; b < 2; ++b)
#pragma unroll
      for (int c = 0; c < 4; ++c)
#pragma unroll
        for (int d = 0; d < 2; ++d) acc[a][b][c][d] = (f32x4){0.f, 0.f, 0.f, 0.f};

  bf16x8 afA[4][2], afB[4][2], bq0[2][2], bq1[2][2];

  // ---- prologue: buf0 tile0 full + buf1-A-h0; then first read set ----
  STGA(0, 0, 0); STGB(0, 0, 0); STGB(0, 1, 0); STGA(0, 1, 0);
  STGA(1, 0, 64);
  VMW(2);
  BAR();
  RD_A0(aA00, aA01, afA);
  RD_B0(aB00, aB01, bq0);

  int kb = 0;
#pragma unroll 1
  for (int j = 0; j < 15; ++j, kb += 128) {
    // P1: MFMA(0,0) buf0 | reads bq1 <- buf0.B.qn1 | stage B1h0
    STGB(1, 0, kb + 64);
    RD_B1(aB00, aB01, bq1);
    LGKM(4); PRIO1(); MMAQ(afA, bq0, 0, 0); PRIO0(); VMW(4); BAR();
    // P2: MFMA(0,1) | reads afB <- buf0.A.qm1 | stage B1h1
    STGB(1, 1, kb + 64);
    RD_A1(aA00, aA01, afB);
    LGKM(8); PRIO1(); MMAQ(afA, bq1, 0, 1); PRIO0(); VMW(4); BAR();
    // P3: MFMA(1,0) | no reads | stage A1h1
    STGA(1, 1, kb + 64);
    LGKM(0); PRIO1(); MMAQ(afB, bq0, 1, 0); PRIO0(); VMW(4); BAR();
    // P4: MFMA(1,1) | reads afA,bq0 <- buf1 | stage A0h0(next)
    STGA(0, 0, kb + 128);
    RD_A0(aA10, aA11, afA);
    RD_B0(aB10, aB11, bq0);
    LGKM(12); PRIO1(); MMAQ(afB, bq1, 1, 1); PRIO0(); VMW(4); BAR();
    // P5: MFMA(0,0) buf1 | reads bq1 <- buf1.B.qn1 | stage B0h0(next)
    STGB(0, 0, kb + 128);
    RD_B1(aB10, aB11, bq1);
    LGKM(4); PRIO1(); MMAQ(afA, bq0, 0, 0); PRIO0(); VMW(4); BAR();
    // P6: MFMA(0,1) | reads afB <- buf1.A.qm1 | stage B0h1(next)
    STGB(0, 1, kb + 128);
    RD_A1(aA10, aA11, afB);
    LGKM(8); PRIO1(); MMAQ(afA, bq1, 0, 1); PRIO0(); VMW(4); BAR();
    // P7: MFMA(1,0) | no reads | stage A0h1(next)
    STGA(0, 1, kb + 128);
    LGKM(0); PRIO1(); MMAQ(afB, bq0, 1, 0); PRIO0(); VMW(4); BAR();
    // P8: MFMA(1,1) | reads afA,bq0 <- next buf0 | stage A1h0(next)
    STGA(1, 0, kb + 192);
    RD_A0(aA00, aA01, afA);
    RD_B0(aB00, aB01, bq0);
    LGKM(12); PRIO1(); MMAQ(afB, bq1, 1, 1); PRIO0(); VMW(4); BAR();
  }
  // ---- tail: tiles 30 (buf0) + 31 (buf1); kb == 1920 ----
  {
    STGB(1, 0, kb + 64);
    RD_B1(aB00, aB01, bq1);
    LGKM(4); PRIO1(); MMAQ(afA, bq0, 0, 0); PRIO0(); VMW(4); BAR();
    STGB(1, 1, kb + 64);
    RD_A1(aA00, aA01, afB);
    LGKM(8); PRIO1(); MMAQ(afA, bq1, 0, 1); PRIO0(); VMW(4); BAR();
    STGA(1, 1, kb + 64);
    LGKM(0); PRIO1(); MMAQ(afB, bq0, 1, 0); PRIO0(); VMW(4); BAR();
    RD_A0(aA10, aA11, afA);
    RD_B0(aB10, aB11, bq0);
    LGKM(12); PRIO1(); MMAQ(afB, bq1, 1, 1); PRIO0(); VMW(2); BAR();
    RD_B1(aB10, aB11, bq1);
    LGKM(4); PRIO1(); MMAQ(afA, bq0, 0, 0); PRIO0(); VMW(0); BAR();
    RD_A1(aA10, aA11, afB);
    LGKM(8); PRIO1(); MMAQ(afA, bq1, 0, 1); PRIO0();
    LGKM(0); PRIO1(); MMAQ(afB, bq0, 1, 0); PRIO0();
    MMAQ(afB, bq1, 1, 1);
  }

  // ---------------- fused epilogue ----------------
  // col = qn*128 + wn*32 + ni*16 + l15 (even=s, odd=g); row = qm*128+wm*64+mi*16+s0*4+r
  __syncthreads();
  float* red = (float*)&lds[0];

#pragma unroll
  for (int qm = 0; qm < 2; ++qm)
#pragma unroll
    for (int mi = 0; mi < 4; ++mi)
#pragma unroll
      for (int r = 0; r < 4; ++r) {
        float num = 0.f, den = 0.f;
#pragma unroll
        for (int qn = 0; qn < 2; ++qn)
#pragma unroll
          for (int ni = 0; ni < 2; ++ni) {
            float v = acc[qm][qn][mi][ni][r];
            float g = __shfl_xor(v, 1);
            float e = __expf(v * SINV);
            num += e * g;
            den += e;
          }
        num += __shfl_xor(num, 2); den += __shfl_xor(den, 2);
        num += __shfl_xor(num, 4); den += __shfl_xor(den, 4);
        num += __shfl_xor(num, 8); den += __shfl_xor(den, 8);
        if (l15 == 0) {
          int slot = qm * 16 + mi * 4 + r;
          red[((wid * 32 + slot) * 4 + s0) * 2 + 0] = num;
          red[((wid * 32 + slot) * 4 + s0) * 2 + 1] = den;
        }
      }
  __syncthreads();
  {
    int rloc = tid >> 1, which = tid & 1;
    int qm = rloc >> 7, wmr = (rloc >> 6) & 1, mi = (rloc >> 4) & 3;
    int lg = (rloc >> 2) & 3, r = rloc & 3;
    int slot = qm * 16 + mi * 4 + r;
    float v = 0.f;
#pragma unroll
    for (int w2 = 0; w2 < 4; ++w2)
      v += red[(((wmr * 4 + w2) * 32 + slot) * 4 + lg) * 2 + which];
    Pnd[((size_t)(brow + rloc) * 8 + bx) * 2 + which] = v;
  }
}

// ---------------- per-row finish ----------------
__global__ __launch_bounds__(256) void k_rowfinal(const float* __restrict__ Pnd,
                                                  float* __restrict__ part) {
  int row = blockIdx.x * 256 + threadIdx.x;
  const float4* p = (const float4*)(Pnd + (size_t)row * 16);
  float num = 0.f, den = 0.f;
#pragma unroll
  for (int i = 0; i < 4; ++i) {
    float4 v = p[i];
    num += v.x + v.z;
    den += v.y + v.w;
  }
  float logit = num / den;
  float ls = (logit >= 0.f) ? -log1pf(__expf(-logit))
                            : (logit - log1pf(__expf(logit)));
  __shared__ float red[4];
#pragma unroll
  for (int off = 32; off > 0; off >>= 1) ls += __shfl_down(ls, off);
  if ((threadIdx.x & 63) == 0) red[threadIdx.x >> 6] = ls;
  __syncthreads();
  if (threadIdx.x == 0) part[blockIdx.x] = red[0] + red[1] + red[2] + red[3];
}

__global__ __launch_bounds__(64) void k_final64(const float* __restrict__ part,
                                                float* __restrict__ out) {
  float v = part[threadIdx.x];
#pragma unroll
  for (int off = 32; off > 0; off >>= 1) v += __shfl_down(v, off);
  if (threadIdx.x == 0) out[0] = v;
}

extern "C" void kernel_launch(void* const* d_in, const int* in_sizes, int n_in,
                              void* d_out, int out_size, void* d_ws, size_t ws_size,
                              hipStream_t stream) {
  const float* D = (const float*)d_in[0];
  const float* S = (const float*)d_in[1];
  const float* W = (const float*)d_in[2];

  char* w = (char*)d_ws;
  u16* Dbf = (u16*)w; w += (size_t)NROWS * DS * 2;       // 67 MB
  u16* Bt = (u16*)w;  w += (size_t)DS * DS * 2;          // 8 MB (interleaved S/V)
  u16* Wbf = (u16*)w; w += (size_t)DS * DS * 2;          // 8 MB
  u16* Sbf = (u16*)w; w += (size_t)MS * DS * 2;          // 4 MB
  float* Pnd = (float*)w; w += (size_t)NROWS * 16 * 4;   // 1 MB
  float* part = (float*)w;                               // 256 B

  (void)hipFuncSetAttribute((const void*)k_gemm8,
                            hipFuncAttributeMaxDynamicSharedMemorySize, 131072);

  k_conv<<<1024, 256, 0, stream>>>(W, Wbf, DS * DS / 4);
  k_conv_S<<<512, 256, 0, stream>>>(S, Sbf, Bt, MS * DS / 4);
  k_conv<<<2048, 256, 0, stream>>>(D, Dbf, NROWS * DS / 4);

  // V = S @ W^T into Bt odd rows (ldc = 4096, base = Bt + 2048)
  k_gemm_bt64<<<dim3(DS / 128, MS / 64), 256, 0, stream>>>(
      Sbf, Wbf, Bt + DS, 2 * DS, DS);

  k_gemm8<<<512, 512, 131072, stream>>>(Dbf, Bt, Pnd);

  k_rowfinal<<<NROWS / 256, 256, 0, stream>>>(Pnd, part);
  k_final64<<<1, 64, 0, stream>>>(part, (float*)d_out);
}